// Round 13
// baseline (21.928 us; speedup 1.0000x reference)
//
#include <hip/hip_runtime.h>
#include <hip/hip_bf16.h>

#define SQ 1024
#define HH 16
#define DK 4
#define EE 64

using short8 = __attribute__((ext_vector_type(8))) short;
using f32x4  = __attribute__((ext_vector_type(4))) float;
using f32x2  = __attribute__((ext_vector_type(2))) float;
using us4    = __attribute__((ext_vector_type(4))) unsigned short;
using us8    = __attribute__((ext_vector_type(8))) unsigned short;
using u32x4  = __attribute__((ext_vector_type(4))) unsigned;

static __device__ inline unsigned short f2bf(float f) {
  return __builtin_bit_cast(unsigned short, __float2bfloat16(f));
}

// Pack two f32 -> {lo: bf16(lo), hi: bf16(hi)} via byte-select (truncation;
// compensated by +log2(1+2^-8) in the QK MFMA C-operand, common-mode in
// num/den so it cancels in the softmax ratio).
static __device__ inline unsigned trunc_pk_bf16(float lo, float hi) {
  return __builtin_amdgcn_perm(__builtin_bit_cast(unsigned, hi),
                               __builtin_bit_cast(unsigned, lo),
                               0x07060302u);
}

// exp2(x) on [-3,3], degree-5 Chebyshev fit, |abs err| <= ~5e-3 (bf16-level;
// P is truncated to bf16 right after). Strictly positive on the interval
// (min ~0.12 near x=-3). Scores satisfy |x| <= 2.886 + 0.006 < 3.
// Evaluated on f32x2 via __builtin_elementwise_fma -> llvm.fma.v2f32 ->
// v_pk_fma_f32 (packed VALU pipe; R12's hand-asm version hit the odd-aligned
// VGPR-pair hazard and produced NaN -- builtin allocates aligned pairs).
#define EA0 1.004041f
#define EA1 0.694527f
#define EA2 0.232307f
#define EA3 0.0543078f
#define EA4 0.0118946f
#define EA5 0.00159291f

static __device__ inline f32x2 poly2(f32x2 t) {
  f32x2 r = __builtin_elementwise_fma(t, (f32x2){EA5, EA5}, (f32x2){EA4, EA4});
  r = __builtin_elementwise_fma(r, t, (f32x2){EA3, EA3});
  r = __builtin_elementwise_fma(r, t, (f32x2){EA2, EA2});
  r = __builtin_elementwise_fma(r, t, (f32x2){EA1, EA1});
  r = __builtin_elementwise_fma(r, t, (f32x2){EA0, EA0});
  return r;
}

static __device__ inline f32x4 exp2_poly(f32x4 s) {
  const f32x2 lo = {s[0], s[1]}, hi = {s[2], s[3]};
  const f32x2 rl = poly2(lo), rh = poly2(hi);
  return (f32x4){rl[0], rl[1], rh[0], rh[1]};
}

// MFMA flash attention, token-split x2, poly-exp. grid = 256 blocks,
// 1024 threads (16 waves). Waves w and w+8 own the same 32 queries; w does
// chunks 0..15, w+8 does 16..31; partials add through LDS (no max-subtract
// needed: |score| <= 2). R10/R11 evidence: trans pipe (16 wave-exps/chunk at
// ~1/8 rate = 256 of ~400 issue-cyc/chunk) is the occupancy-invariant wall
// -> exp moved to the packed-f32 VALU pipe (~80 cyc/chunk).
// Swapped QK^T (A = K-tokens), permuted token->row: mfma1 row i <- token
// 8*(i>>2)+(i&3), mfma2 +4, so QK D (col=lane&15=q, row=4h+r) equals the PV
// A-frag layout (k=8h+j); zero cross-lane ops. V ones-column at n=4 -> den.
__global__ __launch_bounds__(1024) void qattn_mfma(
    const float* __restrict__ x, const float* __restrict__ theta,
    float* __restrict__ y) {
  const int tid = threadIdx.x;
  const int quarter = blockIdx.x & 3;
  const int bh = blockIdx.x >> 2;
  const int hd = bh & (HH - 1);
  const int b = bh >> 4;

  __shared__ __align__(16) unsigned char smem[20496];
  typedef unsigned short afrag_t[16][8];
  typedef unsigned short vfrag_t[4][5][8];
  afrag_t* afrag = reinterpret_cast<afrag_t*>(smem);                 // [32]
  vfrag_t* vfrag = reinterpret_cast<vfrag_t*>(smem + 8192);          // [32]
  unsigned short (*qfrag)[4] =
      reinterpret_cast<unsigned short (*)[4]>(smem + 18432);         // [256]
  unsigned short* zslot = reinterpret_cast<unsigned short*>(smem + 20480);
  f32x4* pex = reinterpret_cast<f32x4*>(smem);  // partial exchange, 16 KB

  const float4 th = *reinterpret_cast<const float4*>(theta);
  const float ct[4] = {__cosf(th.x), __cosf(th.y), __cosf(th.z), __cosf(th.w)};
  const float sc = 0.5f * 1.4426950408889634f;  // softmax scale * log2(e)
  const int q_lo = quarter * 256;

  if (tid < 8) zslot[tid] = 0;
  vfrag[tid >> 5][(tid >> 3) & 3][4][tid & 7] = 0x3F80;  // ones column

  // Stage proj = cos(x)*cos(theta) as bf16 fragments. 1 token/thread.
  const float* xb = x + ((size_t)b * SQ) * EE + hd * DK;
  {
    const int t = tid;
    const float4 v = *reinterpret_cast<const float4*>(xb + (size_t)t * EE);
    const float p[4] = {__cosf(v.x) * ct[0], __cosf(v.y) * ct[1],
                        __cosf(v.z) * ct[2], __cosf(v.w) * ct[3]};
    unsigned short pb[4], qb[4];
#pragma unroll
    for (int d = 0; d < 4; ++d) {
      pb[d] = f2bf(p[d]);
      qb[d] = f2bf(p[d] * sc);
    }
    const int c = t >> 5, tl = t & 31, hq = tl >> 3, j = tl & 7;
    *reinterpret_cast<us4*>(&afrag[c][4 * hq + (j & 3)][(j >= 4) ? 4 : 0]) =
        (us4){pb[0], pb[1], pb[2], pb[3]};
#pragma unroll
    for (int nn = 0; nn < 4; ++nn) vfrag[c][hq][nn][j] = pb[nn];
    const int ql = t - q_lo;
    if ((unsigned)ql < 256u)
      *reinterpret_cast<us4*>(&qfrag[ql][0]) = (us4){qb[0], qb[1], qb[2], qb[3]};
  }
  __syncthreads();

  const int lane = tid & 63;
  const int wid16 = tid >> 6;          // 0..15
  const int wid = wid16 & 7;           // query-group owner 0..7
  const int khalf = wid16 >> 3;        // 0: chunks 0-15, 1: chunks 16-31
  const int n = lane & 15, hg = lane >> 4;

  short8 qf0 = {0, 0, 0, 0, 0, 0, 0, 0}, qf1 = qf0;
  {
    const unsigned short* qa =
        (lane < 16) ? &qfrag[wid * 32 + n][0] : &zslot[0];
    const unsigned short* qb2 =
        (lane < 16) ? &qfrag[wid * 32 + 16 + n][0] : &zslot[0];
    const us4 ta = *reinterpret_cast<const us4*>(qa);
    const us4 tb = *reinterpret_cast<const us4*>(qb2);
#pragma unroll
    for (int i = 0; i < 4; ++i) { qf0[i] = (short)ta[i]; qf1[i] = (short)tb[i]; }
  }

  const unsigned short* aptr = (lane < 16) ? &afrag[0][n][0] : &zslot[0];
  const int astep = (lane < 16) ? 128 : 0;
  const unsigned short* vptr = (n <= 4) ? &vfrag[0][hg][n][0] : &zslot[0];
  const int vstep = (n <= 4) ? 160 : 0;

  f32x4 acc0 = {0.f, 0.f, 0.f, 0.f}, acc1 = acc0;
  const float csh = 0.0056245491938781f;  // log2(1+2^-8) trunc compensation
  const f32x4 cc = {csh, csh, csh, csh};

  const int c0 = khalf * 16;
#pragma unroll 2
  for (int c = c0; c < c0 + 16; ++c) {
    const us8 av = *reinterpret_cast<const us8*>(aptr + c * astep);
    const short8 A1 = {(short)av[0], (short)av[1], (short)av[2], (short)av[3],
                       0, 0, 0, 0};
    const short8 A2 = {(short)av[4], (short)av[5], (short)av[6], (short)av[7],
                       0, 0, 0, 0};
    const f32x4 s1a = __builtin_amdgcn_mfma_f32_16x16x32_bf16(A1, qf0, cc, 0, 0, 0);
    const f32x4 s2a = __builtin_amdgcn_mfma_f32_16x16x32_bf16(A2, qf0, cc, 0, 0, 0);
    const f32x4 s1b = __builtin_amdgcn_mfma_f32_16x16x32_bf16(A1, qf1, cc, 0, 0, 0);
    const f32x4 s2b = __builtin_amdgcn_mfma_f32_16x16x32_bf16(A2, qf1, cc, 0, 0, 0);

    const f32x4 e1a = exp2_poly(s1a);
    const f32x4 e2a = exp2_poly(s2a);
    const f32x4 e1b = exp2_poly(s1b);
    const f32x4 e2b = exp2_poly(s2b);

    u32x4 p0, p1;
    p0[0] = trunc_pk_bf16(e1a[0], e1a[1]);
    p0[1] = trunc_pk_bf16(e1a[2], e1a[3]);
    p0[2] = trunc_pk_bf16(e2a[0], e2a[1]);
    p0[3] = trunc_pk_bf16(e2a[2], e2a[3]);
    p1[0] = trunc_pk_bf16(e1b[0], e1b[1]);
    p1[1] = trunc_pk_bf16(e1b[2], e1b[3]);
    p1[2] = trunc_pk_bf16(e2b[0], e2b[1]);
    p1[3] = trunc_pk_bf16(e2b[2], e2b[3]);
    const short8 PA0 = __builtin_bit_cast(short8, p0);
    const short8 PA1 = __builtin_bit_cast(short8, p1);

    const us8 vv = *reinterpret_cast<const us8*>(vptr + c * vstep);
    const short8 VB = __builtin_bit_cast(short8, vv);
    acc0 = __builtin_amdgcn_mfma_f32_16x16x32_bf16(PA0, VB, acc0, 0, 0, 0);
    acc1 = __builtin_amdgcn_mfma_f32_16x16x32_bf16(PA1, VB, acc1, 0, 0, 0);
  }

  // Token-split combine: waves 8-15 publish partials; waves 0-7 add.
  __syncthreads();  // everyone done reading afrag/vfrag
  if (khalf == 1) {
    const int p = wid * 64 + lane;
    pex[p * 2 + 0] = acc0;
    pex[p * 2 + 1] = acc1;
  }
  __syncthreads();
  if (khalf == 0) {
    const int p = wid * 64 + lane;
    acc0 += pex[p * 2 + 0];
    acc1 += pex[p * 2 + 1];

    // Epilogue: lane holds acc[r] = out[q = qbase+4*hg+r][col n]; n==4 = den.
#pragma unroll
    for (int half = 0; half < 2; ++half) {
      const f32x4 acc = half ? acc1 : acc0;
      const int qbase = q_lo + wid * 32 + half * 16;
#pragma unroll
      for (int r = 0; r < 4; ++r) {
        const float den = __shfl(acc[r], (lane & 48) | 4, 64);
        const float val = acc[r] * (1.0f / den);
        if (n < 4) {
          y[((size_t)(b * SQ + qbase + 4 * hg + r)) * EE + hd * DK + n] = val;
        }
      }
    }
  }
}

// Kernel 2: out[t,e] = bias[e] + sum_j y[t,j] * W[e,j]  (4096 x 64 x 64).
__global__ __launch_bounds__(256) void proj_kernel(
    const float* __restrict__ y, const float* __restrict__ W,
    const float* __restrict__ bias, float* __restrict__ out) {
  const int tid = threadIdx.x;
  __shared__ float Wt[EE][68];       // Wt[j][e] = W[e][j]
  __shared__ float yt[16][68];

  const float4* W4 = reinterpret_cast<const float4*>(W);
#pragma unroll
  for (int k = 0; k < 4; ++k) {
    const int i4 = tid + k * 256;
    const float4 w = W4[i4];
    const int e = i4 >> 4;
    const int j0 = (i4 & 15) * 4;
    Wt[j0 + 0][e] = w.x; Wt[j0 + 1][e] = w.y;
    Wt[j0 + 2][e] = w.z; Wt[j0 + 3][e] = w.w;
  }
  const size_t tok0 = (size_t)blockIdx.x * 16;
  {
    const float4 v = reinterpret_cast<const float4*>(y + tok0 * EE)[tid];
    *reinterpret_cast<float4*>(&yt[tid >> 4][(tid & 15) * 4]) = v;
  }
  __syncthreads();

  const int t = tid >> 4;            // token 0..15
  const int eg = tid & 15;           // 4-column group
  const int e0 = eg * 4;
  f32x4 acc = *reinterpret_cast<const f32x4*>(bias + e0);
#pragma unroll
  for (int jq = 0; jq < 16; ++jq) {
    const f32x4 yv = *reinterpret_cast<const f32x4*>(&yt[t][jq * 4]);
    const f32x4 w0 = *reinterpret_cast<const f32x4*>(&Wt[jq * 4 + 0][e0]);
    const f32x4 w1 = *reinterpret_cast<const f32x4*>(&Wt[jq * 4 + 1][e0]);
    const f32x4 w2 = *reinterpret_cast<const f32x4*>(&Wt[jq * 4 + 2][e0]);
    const f32x4 w3 = *reinterpret_cast<const f32x4*>(&Wt[jq * 4 + 3][e0]);
    acc += yv[0] * w0 + yv[1] * w1 + yv[2] * w2 + yv[3] * w3;
  }
  *reinterpret_cast<f32x4*>(&out[((size_t)tok0 + t) * EE + e0]) = acc;
}

extern "C" void kernel_launch(void* const* d_in, const int* in_sizes, int n_in,
                              void* d_out, int out_size, void* d_ws, size_t ws_size,
                              hipStream_t stream) {
  const float* x     = (const float*)d_in[0];
  const float* theta = (const float*)d_in[1];
  const float* W     = (const float*)d_in[2];
  const float* bias  = (const float*)d_in[3];
  float* out = (float*)d_out;
  float* y   = (float*)d_ws;  // [B,S,E] fp32 = 1 MB attention output

  qattn_mfma<<<256, 1024, 0, stream>>>(x, theta, y);
  proj_kernel<<<256, 256, 0, stream>>>(y, W, bias, out);
}

// Round 14
// 20.023 us; speedup vs baseline: 1.0951x; 1.0951x over previous
//
#include <hip/hip_runtime.h>
#include <hip/hip_bf16.h>

#define SQ 1024
#define HH 16
#define DK 4
#define EE 64

using short8 = __attribute__((ext_vector_type(8))) short;
using f32x4  = __attribute__((ext_vector_type(4))) float;
using us4    = __attribute__((ext_vector_type(4))) unsigned short;
using us8    = __attribute__((ext_vector_type(8))) unsigned short;
using u32x4  = __attribute__((ext_vector_type(4))) unsigned;

static __device__ inline unsigned short f2bf(float f) {
  return __builtin_bit_cast(unsigned short, __float2bfloat16(f));
}

// Pack two f32 -> {lo: bf16(lo), hi: bf16(hi)} via byte-select (truncation;
// compensated by +log2(1+2^-8) in the QK MFMA C-operand, common-mode in
// num/den so it cancels in the softmax ratio). 1 instr per pair.
static __device__ inline unsigned trunc_pk_bf16(float lo, float hi) {
  return __builtin_amdgcn_perm(__builtin_bit_cast(unsigned, hi),
                               __builtin_bit_cast(unsigned, lo),
                               0x07060302u);
}

// MFMA flash attention. grid = 64 bh x 4 quarters = 256 blocks, 512 threads
// (8 waves; R6's best config). Wave w owns 32 queries (2 q-tiles of 16).
// R13 falsified trans-throughput as the wall; R10 counters point to VALU
// *issue volume* (~230 cyc/chunk vs ~90 expected) -> this round eliminates
// per-chunk fragment-assembly VALU by construction:
//   - a1frag/a2frag hold the two QK A-operand halves as us4; ds_read_b64
//     lands exactly the live half, zeros placed via shufflevector (register
//     placement, no v_bfe/v_lshl element chains).
//   - P->bf16 via 8 v_perm per chunk (trunc_pk, R9-validated).
// Swapped QK^T (A = K-tokens), permuted token->row: mfma1 row i <- token
// 8*(i>>2)+(i&3), mfma2 +4, so QK D (col=lane&15=q, row=4h+r) equals the PV
// A-frag layout (k=8h+j); zero cross-lane ops. V ones-column at n=4 -> den.
__global__ __launch_bounds__(512) void qattn_mfma(
    const float* __restrict__ x, const float* __restrict__ theta,
    float* __restrict__ y) {
  const int tid = threadIdx.x;
  const int quarter = blockIdx.x & 3;
  const int bh = blockIdx.x >> 2;
  const int hd = bh & (HH - 1);
  const int b = bh >> 4;

  __shared__ __align__(16) us4 a1frag[32][16];                // 4 KB
  __shared__ __align__(16) us4 a2frag[32][16];                // 4 KB
  __shared__ __align__(16) unsigned short vfrag[32][4][5][8]; // 10 KB
  __shared__ __align__(16) us4 qfrag[256];                    // 2 KB
  __shared__ __align__(16) us4 zq;                            // 8B zeros

  const float4 th = *reinterpret_cast<const float4*>(theta);
  const float ct[4] = {__cosf(th.x), __cosf(th.y), __cosf(th.z), __cosf(th.w)};
  const float sc = 0.5f * 1.4426950408889634f;  // softmax scale * log2(e)
  const int q_lo = quarter * 256;

  if (tid == 0) zq = (us4){0, 0, 0, 0};
#pragma unroll
  for (int k = 0; k < 2; ++k) {  // ones column (1024 entries)
    const int e = tid + k * 512;
    vfrag[e >> 5][(e >> 3) & 3][4][e & 7] = 0x3F80;
  }

  // Stage proj = cos(x)*cos(theta) as bf16 fragments. 2 tokens/thread.
  const float* xb = x + ((size_t)b * SQ) * EE + hd * DK;
#pragma unroll
  for (int k = 0; k < 2; ++k) {
    const int t = tid + k * 512;
    const float4 v = *reinterpret_cast<const float4*>(xb + (size_t)t * EE);
    const float p[4] = {__cosf(v.x) * ct[0], __cosf(v.y) * ct[1],
                        __cosf(v.z) * ct[2], __cosf(v.w) * ct[3]};
    unsigned short pb[4], qb[4];
#pragma unroll
    for (int d = 0; d < 4; ++d) {
      pb[d] = f2bf(p[d]);
      qb[d] = f2bf(p[d] * sc);
    }
    const int c = t >> 5, tl = t & 31, grp = tl >> 3, pos = tl & 7;
    const us4 pv4 = (us4){pb[0], pb[1], pb[2], pb[3]};
    us4* dst = (pos < 4) ? &a1frag[c][4 * grp + pos]
                         : &a2frag[c][4 * grp + (pos - 4)];
    *dst = pv4;  // one predicated-address ds_write_b64
#pragma unroll
    for (int nn = 0; nn < 4; ++nn) vfrag[c][grp][nn][pos] = pb[nn];
    const int ql = t - q_lo;
    if ((unsigned)ql < 256u) qfrag[ql] = (us4){qb[0], qb[1], qb[2], qb[3]};
  }
  __syncthreads();

  const int lane = tid & 63;
  const int wid = tid >> 6;            // 8 waves, 32 queries each
  const int n = lane & 15, hg = lane >> 4;

  const us4 ZZ = (us4){0, 0, 0, 0};

  // Two Q fragments (B-operand): lanes<16 carry d=0..3, rest zero.
  const us4 q0v = (lane < 16) ? qfrag[wid * 32 + n] : ZZ;
  const us4 q1v = (lane < 16) ? qfrag[wid * 32 + 16 + n] : ZZ;
  const short8 qf0 = __builtin_bit_cast(
      short8, __builtin_shufflevector(q0v, ZZ, 0, 1, 2, 3, 4, 5, 6, 7));
  const short8 qf1 = __builtin_bit_cast(
      short8, __builtin_shufflevector(q1v, ZZ, 0, 1, 2, 3, 4, 5, 6, 7));

  const us4* a1p = (lane < 16) ? &a1frag[0][n] : &zq;
  const us4* a2p = (lane < 16) ? &a2frag[0][n] : &zq;
  const int astep = (lane < 16) ? 16 : 0;  // us4 elements per chunk
  const unsigned short* vptr = (n <= 4) ? &vfrag[0][hg][n][0] : (unsigned short*)&zq;
  const int vstep = (n <= 4) ? 160 : 0;

  f32x4 acc0 = {0.f, 0.f, 0.f, 0.f}, acc1 = acc0;
  const float csh = 0.0056245491938781f;  // log2(1+2^-8) trunc compensation
  const f32x4 cc = {csh, csh, csh, csh};

#pragma unroll 2
  for (int c = 0; c < 32; ++c) {
    const us4 a1 = a1p[c * astep];
    const us4 a2 = a2p[c * astep];
    const short8 A1 = __builtin_bit_cast(
        short8, __builtin_shufflevector(a1, ZZ, 0, 1, 2, 3, 4, 5, 6, 7));
    const short8 A2 = __builtin_bit_cast(
        short8, __builtin_shufflevector(a2, ZZ, 0, 1, 2, 3, 4, 5, 6, 7));

    const f32x4 s1a = __builtin_amdgcn_mfma_f32_16x16x32_bf16(A1, qf0, cc, 0, 0, 0);
    const f32x4 s2a = __builtin_amdgcn_mfma_f32_16x16x32_bf16(A2, qf0, cc, 0, 0, 0);
    const f32x4 s1b = __builtin_amdgcn_mfma_f32_16x16x32_bf16(A1, qf1, cc, 0, 0, 0);
    const f32x4 s2b = __builtin_amdgcn_mfma_f32_16x16x32_bf16(A2, qf1, cc, 0, 0, 0);

    u32x4 p0, p1;
    p0[0] = trunc_pk_bf16(__builtin_amdgcn_exp2f(s1a[0]),
                          __builtin_amdgcn_exp2f(s1a[1]));
    p0[1] = trunc_pk_bf16(__builtin_amdgcn_exp2f(s1a[2]),
                          __builtin_amdgcn_exp2f(s1a[3]));
    p0[2] = trunc_pk_bf16(__builtin_amdgcn_exp2f(s2a[0]),
                          __builtin_amdgcn_exp2f(s2a[1]));
    p0[3] = trunc_pk_bf16(__builtin_amdgcn_exp2f(s2a[2]),
                          __builtin_amdgcn_exp2f(s2a[3]));
    p1[0] = trunc_pk_bf16(__builtin_amdgcn_exp2f(s1b[0]),
                          __builtin_amdgcn_exp2f(s1b[1]));
    p1[1] = trunc_pk_bf16(__builtin_amdgcn_exp2f(s1b[2]),
                          __builtin_amdgcn_exp2f(s1b[3]));
    p1[2] = trunc_pk_bf16(__builtin_amdgcn_exp2f(s2b[0]),
                          __builtin_amdgcn_exp2f(s2b[1]));
    p1[3] = trunc_pk_bf16(__builtin_amdgcn_exp2f(s2b[2]),
                          __builtin_amdgcn_exp2f(s2b[3]));
    const short8 PA0 = __builtin_bit_cast(short8, p0);
    const short8 PA1 = __builtin_bit_cast(short8, p1);

    const us8 vv = *reinterpret_cast<const us8*>(vptr + c * vstep);
    const short8 VB = __builtin_bit_cast(short8, vv);
    acc0 = __builtin_amdgcn_mfma_f32_16x16x32_bf16(PA0, VB, acc0, 0, 0, 0);
    acc1 = __builtin_amdgcn_mfma_f32_16x16x32_bf16(PA1, VB, acc1, 0, 0, 0);
  }

  // Epilogue: lane holds acc[r] = out[q = qbase+4*hg+r][col n]; n==4 -> den.
#pragma unroll
  for (int half = 0; half < 2; ++half) {
    const f32x4 acc = half ? acc1 : acc0;
    const int qbase = q_lo + wid * 32 + half * 16;
#pragma unroll
    for (int r = 0; r < 4; ++r) {
      const float den = __shfl(acc[r], (lane & 48) | 4, 64);
      const float val = acc[r] * (1.0f / den);
      if (n < 4) {
        y[((size_t)(b * SQ + qbase + 4 * hg + r)) * EE + hd * DK + n] = val;
      }
    }
  }
}

// Kernel 2: out[t,e] = bias[e] + sum_j y[t,j] * W[e,j]  (4096 x 64 x 64).
__global__ __launch_bounds__(256) void proj_kernel(
    const float* __restrict__ y, const float* __restrict__ W,
    const float* __restrict__ bias, float* __restrict__ out) {
  const int tid = threadIdx.x;
  __shared__ float Wt[EE][68];       // Wt[j][e] = W[e][j]
  __shared__ float yt[16][68];

  const float4* W4 = reinterpret_cast<const float4*>(W);
#pragma unroll
  for (int k = 0; k < 4; ++k) {
    const int i4 = tid + k * 256;
    const float4 w = W4[i4];
    const int e = i4 >> 4;
    const int j0 = (i4 & 15) * 4;
    Wt[j0 + 0][e] = w.x; Wt[j0 + 1][e] = w.y;
    Wt[j0 + 2][e] = w.z; Wt[j0 + 3][e] = w.w;
  }
  const size_t tok0 = (size_t)blockIdx.x * 16;
  {
    const float4 v = reinterpret_cast<const float4*>(y + tok0 * EE)[tid];
    *reinterpret_cast<float4*>(&yt[tid >> 4][(tid & 15) * 4]) = v;
  }
  __syncthreads();

  const int t = tid >> 4;            // token 0..15
  const int eg = tid & 15;           // 4-column group
  const int e0 = eg * 4;
  f32x4 acc = *reinterpret_cast<const f32x4*>(bias + e0);
#pragma unroll
  for (int jq = 0; jq < 16; ++jq) {
    const f32x4 yv = *reinterpret_cast<const f32x4*>(&yt[t][jq * 4]);
    const f32x4 w0 = *reinterpret_cast<const f32x4*>(&Wt[jq * 4 + 0][e0]);
    const f32x4 w1 = *reinterpret_cast<const f32x4*>(&Wt[jq * 4 + 1][e0]);
    const f32x4 w2 = *reinterpret_cast<const f32x4*>(&Wt[jq * 4 + 2][e0]);
    const f32x4 w3 = *reinterpret_cast<const f32x4*>(&Wt[jq * 4 + 3][e0]);
    acc += yv[0] * w0 + yv[1] * w1 + yv[2] * w2 + yv[3] * w3;
  }
  *reinterpret_cast<f32x4*>(&out[((size_t)tok0 + t) * EE + e0]) = acc;
}

extern "C" void kernel_launch(void* const* d_in, const int* in_sizes, int n_in,
                              void* d_out, int out_size, void* d_ws, size_t ws_size,
                              hipStream_t stream) {
  const float* x     = (const float*)d_in[0];
  const float* theta = (const float*)d_in[1];
  const float* W     = (const float*)d_in[2];
  const float* bias  = (const float*)d_in[3];
  float* out = (float*)d_out;
  float* y   = (float*)d_ws;  // [B,S,E] fp32 = 1 MB attention output

  qattn_mfma<<<256, 512, 0, stream>>>(x, theta, y);
  proj_kernel<<<256, 256, 0, stream>>>(y, W, bias, out);
}